// Round 7
// baseline (118.446 us; speedup 1.0000x reference)
//
#include <hip/hip_runtime.h>
#include <hip/hip_bf16.h>

// BarlowTwins loss: logits[b,n,m] = sum_s z1[b,s,n]*z2[b,s,m]  (B=8, S=256, N=M=2048)
// loss = mean_{b,m}( LSE_n(logits[b,:,m]) - logits[b,m,m] )
//
// Round-7 = round-4 (32.2us validated: 256 blocks x 512 thr, 1/CU lockstep, FETCH~cold)
// + software-pipelined exp: exp(tile t-1) is hand-interleaved into tile t's MFMA stream
// (even/odd acc pairs, all indices compile-time). TRANS pipe hides under matrix pipe.
//  - b = bid&7 (XCD-aligned); wave (wm,wn): 64 m (2 strips, B-frags 128 VGPR) x 256 n.
//  - A staged f32->bf16->LDS stride 264 (0 bank conflicts measured rounds 2/4/5).
//  - Double buffer, one barrier per tile; loads 2 tiles ahead.
//  - No max tracking: z2 pre-scaled by log2e, acc init -96, exp2 directly on acc.
//  - LSE - diag = ln2*(log2(S) - diag_acc); offset cancels.

#define NN 2048
#define SK 256
#define LDST 264
#define LOG2E 1.4426950408889634f
#define LN2   0.6931471805599453f
#define COFF  96.0f

typedef __attribute__((ext_vector_type(8))) short short8;
typedef __attribute__((ext_vector_type(16))) float f32x16;

__device__ __forceinline__ unsigned short f2bf(float f) {
    __hip_bfloat16 h = __float2bfloat16(f);
    unsigned short u; __builtin_memcpy(&u, &h, 2); return u;
}

__device__ __forceinline__ float exp2g(float x) {
#if __has_builtin(__builtin_amdgcn_exp2f)
    return __builtin_amdgcn_exp2f(x);
#else
    return exp2f(x);
#endif
}

__device__ __forceinline__ float log2g(float x) {
#if __has_builtin(__builtin_amdgcn_logf)
    return __builtin_amdgcn_logf(x);
#else
    return log2f(x);
#endif
}

__global__ __launch_bounds__(512, 2) void gemm_lse_kernel(
    const float* __restrict__ z1, const float* __restrict__ z2,
    float* __restrict__ ws_sum, float* __restrict__ ws_diag)
{
    __shared__ unsigned short lds[2][64 * LDST];   // 2 x 33.8 KB

    const int bid  = blockIdx.x;
    const int b    = bid & 7;          // XCD-aligned batch
    const int tile = bid >> 3;
    const int mb   = tile & 7;         // 8 m-blocks of 256
    const int ns   = tile >> 3;        // 4 n-splits of 512
    const int tid  = threadIdx.x;
    const int lane = tid & 63;
    const int w    = tid >> 6;
    const int wm   = w >> 1;           // 0..3
    const int wn   = w & 1;            // 0..1
    const int col  = lane & 31;
    const int kg   = lane >> 5;

    const int m0      = mb * 256 + wm * 64;   // strip0; strip1 = +32
    const int mcol0   = m0 + col;
    const int mcol1   = m0 + 32 + col;
    const int n_start = ns * 512;

    const float* z1b = z1 + (size_t)b * SK * NN;
    const float* z2b = z2 + (size_t)b * SK * NN;

    // ---- A staging helpers (identical to round 4) ----
    float apf[4][8];
    auto load_A = [&](int t) {
        const int nbase = n_start + 64 * t;
        #pragma unroll
        for (int r = 0; r < 4; ++r) {
            const int sg = 8 * r + w;  // s-group 0..31
            const float* p = z1b + (size_t)(sg * 8) * NN + nbase + lane;
            #pragma unroll
            for (int j = 0; j < 8; ++j) apf[r][j] = p[(size_t)j * NN];
        }
    };
    auto store_A = [&](unsigned short* buf) {
        #pragma unroll
        for (int r = 0; r < 4; ++r) {
            const int sg = 8 * r + w;
            short8 pk;
            #pragma unroll
            for (int j = 0; j < 8; ++j) pk[j] = (short)f2bf(apf[r][j]);
            *(short8*)(buf + lane * LDST + sg * 8) = pk;
        }
    };

    // ---- prologue: stage tiles 0,1; build B fragments while loads land ----
    load_A(0);
    store_A(lds[0]);
    load_A(1);

    short8 bf0[16], bf1[16];
    #pragma unroll
    for (int ks = 0; ks < 16; ++ks) {
        short8 p0, p1;
        #pragma unroll
        for (int j = 0; j < 8; ++j) {
            const int s = ks * 16 + kg * 8 + j;
            p0[j] = (short)f2bf(z2b[s * NN + mcol0] * LOG2E);
            p1[j] = (short)f2bf(z2b[s * NN + mcol1] * LOG2E);
        }
        bf0[ks] = p0; bf1[ks] = p1;
    }

    float srun0 = 0.0f, srun1 = 0.0f;
    f32x16 accE0, accE1, accO0, accO1;   // even/odd tile accumulator pairs

    __syncthreads();   // buf0 visible

// Tile T: MFMA into C0/C1 while exp-summing the PREVIOUS tile's P0/P1 (interleaved,
// all indices compile-time). Then stage t+1, prefetch t+2, diag capture, barrier.
#define TILE_BODY(T, C0, C1, P0, P1, DOP)                                           \
    {                                                                               \
        const unsigned short* abase = lds[(T) & 1] + (32 * wn + col) * LDST + kg * 8; \
        _Pragma("unroll")                                                           \
        for (int r = 0; r < 16; ++r) { C0[r] = -COFF; C1[r] = -COFF; }              \
        float f0 = 0, f1 = 0, f2 = 0, f3 = 0, g0 = 0, g1 = 0, g2 = 0, g3 = 0;       \
        _Pragma("unroll")                                                           \
        for (int ks = 0; ks < 16; ++ks) {                                           \
            short8 af = *(const short8*)(abase + ks * 16);                          \
            C0 = __builtin_amdgcn_mfma_f32_32x32x16_bf16(af, bf0[ks], C0, 0, 0, 0); \
            C1 = __builtin_amdgcn_mfma_f32_32x32x16_bf16(af, bf1[ks], C1, 0, 0, 0); \
            if ((DOP) && (ks & 1)) {                                                \
                const int c = ks >> 1;                                              \
                if (c < 4) {                                                        \
                    f0 += exp2g(P0[(4 * c + 0) & 15]);                              \
                    f1 += exp2g(P0[(4 * c + 1) & 15]);                              \
                    f2 += exp2g(P0[(4 * c + 2) & 15]);                              \
                    f3 += exp2g(P0[(4 * c + 3) & 15]);                              \
                } else {                                                            \
                    g0 += exp2g(P1[(4 * c + 0) & 15]);                              \
                    g1 += exp2g(P1[(4 * c + 1) & 15]);                              \
                    g2 += exp2g(P1[(4 * c + 2) & 15]);                              \
                    g3 += exp2g(P1[(4 * c + 3) & 15]);                              \
                }                                                                   \
            }                                                                       \
        }                                                                           \
        if (DOP) { srun0 += (f0 + f1) + (f2 + f3); srun1 += (g0 + g1) + (g2 + g3); } \
        if ((T) < 7) store_A(lds[((T) + 1) & 1]);                                   \
        if ((T) < 6) load_A((T) + 2);                                               \
        const int nsub = n_start + 64 * (T) + 32 * wn;                              \
        if (nsub == m0) {                                                           \
            _Pragma("unroll")                                                       \
            for (int r = 0; r < 16; ++r) {                                          \
                const int row = (r & 3) + 8 * (r >> 2) + 4 * kg;                    \
                if (row == col) ws_diag[b * NN + mcol0] = C0[r];                    \
            }                                                                       \
        }                                                                           \
        if (nsub == m0 + 32) {                                                      \
            _Pragma("unroll")                                                       \
            for (int r = 0; r < 16; ++r) {                                          \
                const int row = (r & 3) + 8 * (r >> 2) + 4 * kg;                    \
                if (row == col) ws_diag[b * NN + mcol1] = C1[r];                    \
            }                                                                       \
        }                                                                           \
        __syncthreads();                                                            \
    }

    TILE_BODY(0, accE0, accE1, accO0, accO1, false)
    TILE_BODY(1, accO0, accO1, accE0, accE1, true)
    TILE_BODY(2, accE0, accE1, accO0, accO1, true)
    TILE_BODY(3, accO0, accO1, accE0, accE1, true)
    TILE_BODY(4, accE0, accE1, accO0, accO1, true)
    TILE_BODY(5, accO0, accO1, accE0, accE1, true)
    TILE_BODY(6, accE0, accE1, accO0, accO1, true)
    TILE_BODY(7, accO0, accO1, accE0, accE1, true)
#undef TILE_BODY

    // drain: exp-sum of tile 7's accumulators (accO pair)
    {
        float f0 = 0, f1 = 0, f2 = 0, f3 = 0, g0 = 0, g1 = 0, g2 = 0, g3 = 0;
        #pragma unroll
        for (int r = 0; r < 16; r += 4) {
            f0 += exp2g(accO0[r]);     f1 += exp2g(accO0[r + 1]);
            f2 += exp2g(accO0[r + 2]); f3 += exp2g(accO0[r + 3]);
            g0 += exp2g(accO1[r]);     g1 += exp2g(accO1[r + 1]);
            g2 += exp2g(accO1[r + 2]); g3 += exp2g(accO1[r + 3]);
        }
        srun0 += (f0 + f1) + (f2 + f3);
        srun1 += (g0 + g1) + (g2 + g3);
    }

    srun0 += __shfl_xor(srun0, 32);
    srun1 += __shfl_xor(srun1, 32);
    if (kg == 0) {
        const int slot = ns * 2 + wn;   // 8 n-partials per (b,m)
        ws_sum[(b * 8 + slot) * NN + mcol0] = srun0;
        ws_sum[(b * 8 + slot) * NN + mcol1] = srun1;
    }
}

__global__ __launch_bounds__(256) void merge_kernel(
    const float* __restrict__ ws_sum, const float* __restrict__ ws_diag,
    float* __restrict__ partial)
{
    const int gid = blockIdx.x * 256 + threadIdx.x;   // 0..16383
    const int b = gid >> 11, m = gid & (NN - 1);

    float S = 0.0f;
    #pragma unroll
    for (int slot = 0; slot < 8; ++slot)
        S += ws_sum[(b * 8 + slot) * NN + m];
    float c = log2g(S) - ws_diag[gid];   // (LSE' - diag') in log2 units

    #pragma unroll
    for (int d = 1; d < 64; d <<= 1) c += __shfl_xor(c, d);
    __shared__ float red[4];
    if ((threadIdx.x & 63) == 0) red[threadIdx.x >> 6] = c;
    __syncthreads();
    if (threadIdx.x == 0)
        partial[blockIdx.x] = red[0] + red[1] + red[2] + red[3];
}

__global__ void final_kernel(const float* __restrict__ partial, float* __restrict__ out)
{
    float v = partial[threadIdx.x];   // 64 threads
    #pragma unroll
    for (int d = 1; d < 64; d <<= 1) v += __shfl_xor(v, d);
    if (threadIdx.x == 0) out[0] = v * (LN2 / 16384.0f);
}

extern "C" void kernel_launch(void* const* d_in, const int* in_sizes, int n_in,
                              void* d_out, int out_size, void* d_ws, size_t ws_size,
                              hipStream_t stream)
{
    const float* z1 = (const float*)d_in[0];
    const float* z2 = (const float*)d_in[1];
    float* ws  = (float*)d_ws;
    float* out = (float*)d_out;

    // ws layout (floats): sum[8][8][2048] | diag[8][2048] | partial[64]
    float* ws_sum  = ws;
    float* ws_diag = ws + 131072;
    float* ws_part = ws + 147456;

    gemm_lse_kernel<<<dim3(256), dim3(512), 0, stream>>>(z1, z2, ws_sum, ws_diag);
    merge_kernel<<<dim3(64), dim3(256), 0, stream>>>(ws_sum, ws_diag, ws_part);
    final_kernel<<<dim3(1), dim3(64), 0, stream>>>(ws_part, out);
}

// Round 8
// 40.551 us; speedup vs baseline: 2.9209x; 2.9209x over previous
//
#include <hip/hip_runtime.h>
#include <hip/hip_bf16.h>

// BarlowTwins loss: logits[b,n,m] = sum_s z1[b,s,n]*z2[b,s,m]  (B=8, S=256, N=M=2048)
// loss = mean_{b,m}( LSE_n(logits[b,:,m]) - logits[b,m,m] )
//
// Round-8:
//  K1 prepass (round-3 verified): f32 [b][s][n] -> bf16 [b][n][s] K-major; z2 x log2e.
//  K2 gemm: 256 blocks x 512 thr (1/CU lockstep, validated memory shape), but staging is
//     now 32 global_load_lds_dwordx4 per 64n-tile (async, no VGPR/cvt/ds_write path).
//     LDS rows 512B linear (required by global_load_lds) + rule-21 both-sides XOR swizzle:
//       source off16 = (lane&31) ^ (row&31);  read off16 = (2ks+kg) ^ (row&31)
//     -> read slots are a 32-permutation per wave-half (conflict-free), and recover the
//     logical K-major fragment ks*16+kg*8 (round-3-verified mapping).
//     B-frags: 32 dwordx4/lane from z2t (round-3 verified). acc init -96, exp2-sum,
//     no max tracking. Double LDS buffer, stage t+1 issued before compute t.
//  K3/K4 merge/final: log2(S) - diag (offset cancels), mean * ln2.

#define NN 2048
#define SK 256
#define LOG2E 1.4426950408889634f
#define LN2   0.6931471805599453f
#define COFF  96.0f

typedef __attribute__((ext_vector_type(8))) short short8;
typedef __attribute__((ext_vector_type(16))) float f32x16;

__device__ __forceinline__ unsigned short f2bf(float f) {
    __hip_bfloat16 h = __float2bfloat16(f);
    unsigned short u; __builtin_memcpy(&u, &h, 2); return u;
}

__device__ __forceinline__ float exp2g(float x) {
#if __has_builtin(__builtin_amdgcn_exp2f)
    return __builtin_amdgcn_exp2f(x);
#else
    return exp2f(x);
#endif
}

__device__ __forceinline__ float log2g(float x) {
#if __has_builtin(__builtin_amdgcn_logf)
    return __builtin_amdgcn_logf(x);
#else
    return log2f(x);
#endif
}

__device__ __forceinline__ void gload16(const unsigned short* g, unsigned short* l) {
    // async global->LDS, 16B x 64 lanes; LDS dest = wave-uniform base + lane*16
    __builtin_amdgcn_global_load_lds(
        (const __attribute__((address_space(1))) unsigned int*)(g),
        (__attribute__((address_space(3))) unsigned int*)(l),
        16, 0, 0);
}

// ---------------- K1: transpose + cvt prepass (round-3 verified) ----------------
__global__ __launch_bounds__(256) void transpose_kernel(
    const float* __restrict__ z1, const float* __restrict__ z2,
    unsigned short* __restrict__ z1t, unsigned short* __restrict__ z2t)
{
    __shared__ float lds[64][65];

    const int bid  = blockIdx.x;        // 2048 blocks
    const int arr  = bid >> 10;         // 0: z1, 1: z2
    const int rest = bid & 1023;
    const int b    = rest >> 7;
    const int st   = (rest >> 5) & 3;   // s-tile (4 x 64)
    const int nt   = rest & 31;         // n-tile (32 x 64)

    const float* in = (arr ? z2 : z1) + (size_t)b * SK * NN + (size_t)(st * 64) * NN + nt * 64;
    unsigned short* out = (arr ? z2t : z1t) + (size_t)b * NN * SK + (size_t)(nt * 64) * SK + st * 64;
    const float scale = arr ? LOG2E : 1.0f;

    const int tid = threadIdx.x;
    const int n4 = tid & 15, sl = tid >> 4;
    #pragma unroll
    for (int r = 0; r < 4; ++r) {
        const int s = r * 16 + sl;
        float4 v = *(const float4*)(in + (size_t)s * NN + n4 * 4);
        lds[n4 * 4 + 0][s] = v.x * scale;
        lds[n4 * 4 + 1][s] = v.y * scale;
        lds[n4 * 4 + 2][s] = v.z * scale;
        lds[n4 * 4 + 3][s] = v.w * scale;
    }
    __syncthreads();

    const int nr = tid >> 2, q = tid & 3;
    short8 o0, o1;
    #pragma unroll
    for (int i = 0; i < 8; ++i) o0[i] = (short)f2bf(lds[nr][q * 16 + i]);
    #pragma unroll
    for (int i = 0; i < 8; ++i) o1[i] = (short)f2bf(lds[nr][q * 16 + 8 + i]);
    *(short8*)(out + (size_t)nr * SK + q * 16)     = o0;
    *(short8*)(out + (size_t)nr * SK + q * 16 + 8) = o1;
}

// ---------------- K2: fused GEMM + exp2-sum, global_load_lds staging ----------------
__global__ __launch_bounds__(512, 2) void gemm_lse_kernel(
    const unsigned short* __restrict__ z1t, const unsigned short* __restrict__ z2t,
    float* __restrict__ ws_sum, float* __restrict__ ws_diag)
{
    __shared__ unsigned short ldsA[2][64 * SK];   // 2 x 32 KB, linear 512B rows

    const int bid  = blockIdx.x;
    const int b    = bid & 7;          // XCD-aligned batch
    const int tile = bid >> 3;
    const int mb   = tile & 7;         // 8 m-blocks of 256
    const int ns   = tile >> 3;        // 4 n-splits of 512
    const int tid  = threadIdx.x;
    const int lane = tid & 63;
    const int w    = tid >> 6;
    const int wm   = w >> 1;           // 0..3
    const int wn   = w & 1;            // 0..1
    const int col  = lane & 31;
    const int kg   = lane >> 5;

    const int m0      = mb * 256 + wm * 64;   // strip0; strip1 = +32
    const int mcol0   = m0 + col;
    const int mcol1   = m0 + 32 + col;
    const int n_start = ns * 512;

    const unsigned short* z1b = z1t + (size_t)b * NN * SK;
    const unsigned short* z2b = z2t + (size_t)b * NN * SK;

    // ---- async A staging: tile t = 64 rows x 512B; wave w stages rows 8w..8w+7 ----
    auto stage = [&](int t, int bufi) {
        unsigned short* buf = &ldsA[bufi][0];
        const unsigned short* src = z1b + (size_t)(n_start + 64 * t) * SK;
        #pragma unroll
        for (int q = 0; q < 4; ++q) {
            const int r0   = 8 * w + 2 * q;            // wave-uniform row pair
            const int row  = r0 + (lane >> 5);
            const int off16 = (lane & 31) ^ (row & 31); // pre-swizzled source slot
            gload16(src + (size_t)row * SK + off16 * 8, buf + (size_t)r0 * SK);
        }
    };

    stage(0, 0);   // async; drained by first barrier

    // ---- B fragments: 2 strips x K=256, direct dwordx4 from K-major z2t ----
    short8 bf0[16], bf1[16];
    {
        const unsigned short* b0p = z2b + (size_t)mcol0 * SK + kg * 8;
        const unsigned short* b1p = b0p + 32 * SK;
        #pragma unroll
        for (int ks = 0; ks < 16; ++ks) {
            bf0[ks] = *(const short8*)(b0p + ks * 16);
            bf1[ks] = *(const short8*)(b1p + ks * 16);
        }
    }

    float srun0 = 0.0f, srun1 = 0.0f;

    __syncthreads();   // vmcnt(0) drain: buf0 staged, B-frags landed

    for (int t = 0; t < 8; ++t) {
        if (t < 7) stage(t + 1, (t + 1) & 1);   // async, overlaps compute below

        // this wave's 32-row subtile: rows 32*wn+col of the tile
        const int rowi  = 32 * wn + col;
        const unsigned short* abase = &ldsA[t & 1][0] + (size_t)rowi * SK;
        const int xr = rowi & 31;               // == col for both wn

        f32x16 acc0, acc1;
        #pragma unroll
        for (int r = 0; r < 16; ++r) { acc0[r] = -COFF; acc1[r] = -COFF; }

        #pragma unroll
        for (int ks = 0; ks < 16; ++ks) {
            // logical frag slot 2ks+kg (16B units), swizzle-read with ^xr
            short8 af = *(const short8*)(abase + ((((ks << 1) | kg) ^ xr) << 3));
            acc0 = __builtin_amdgcn_mfma_f32_32x32x16_bf16(af, bf0[ks], acc0, 0, 0, 0);
            acc1 = __builtin_amdgcn_mfma_f32_32x32x16_bf16(af, bf1[ks], acc1, 0, 0, 0);
        }

        // diagonal capture (acc = logit' - 96; offset cancels in merge)
        const int nsub = n_start + 64 * t + 32 * wn;
        if (nsub == m0) {
            #pragma unroll
            for (int r = 0; r < 16; ++r) {
                const int row = (r & 3) + 8 * (r >> 2) + 4 * kg;
                if (row == col) ws_diag[b * NN + mcol0] = acc0[r];
            }
        }
        if (nsub == m0 + 32) {
            #pragma unroll
            for (int r = 0; r < 16; ++r) {
                const int row = (r & 3) + 8 * (r >> 2) + 4 * kg;
                if (row == col) ws_diag[b * NN + mcol1] = acc1[r];
            }
        }

        // exp2-sum, 4 independent chains per strip
        {
            float e0 = 0, e1 = 0, e2 = 0, e3 = 0;
            #pragma unroll
            for (int r = 0; r < 16; r += 4) {
                e0 += exp2g(acc0[r]);     e1 += exp2g(acc0[r + 1]);
                e2 += exp2g(acc0[r + 2]); e3 += exp2g(acc0[r + 3]);
            }
            srun0 += (e0 + e1) + (e2 + e3);
        }
        {
            float e0 = 0, e1 = 0, e2 = 0, e3 = 0;
            #pragma unroll
            for (int r = 0; r < 16; r += 4) {
                e0 += exp2g(acc1[r]);     e1 += exp2g(acc1[r + 1]);
                e2 += exp2g(acc1[r + 2]); e3 += exp2g(acc1[r + 3]);
            }
            srun1 += (e0 + e1) + (e2 + e3);
        }

        __syncthreads();   // drains stage(t+1); all waves done reading buf[t&1]
    }

    srun0 += __shfl_xor(srun0, 32);
    srun1 += __shfl_xor(srun1, 32);
    if (kg == 0) {
        const int slot = ns * 2 + wn;   // 8 n-partials per (b,m)
        ws_sum[(b * 8 + slot) * NN + mcol0] = srun0;
        ws_sum[(b * 8 + slot) * NN + mcol1] = srun1;
    }
}

// ---------------- K3/K4: merge + reduce ----------------
__global__ __launch_bounds__(256) void merge_kernel(
    const float* __restrict__ ws_sum, const float* __restrict__ ws_diag,
    float* __restrict__ partial)
{
    const int gid = blockIdx.x * 256 + threadIdx.x;   // 0..16383
    const int b = gid >> 11, m = gid & (NN - 1);

    float S = 0.0f;
    #pragma unroll
    for (int slot = 0; slot < 8; ++slot)
        S += ws_sum[(b * 8 + slot) * NN + m];
    float c = log2g(S) - ws_diag[gid];   // (LSE' - diag') in log2 units

    #pragma unroll
    for (int d = 1; d < 64; d <<= 1) c += __shfl_xor(c, d);
    __shared__ float red[4];
    if ((threadIdx.x & 63) == 0) red[threadIdx.x >> 6] = c;
    __syncthreads();
    if (threadIdx.x == 0)
        partial[blockIdx.x] = red[0] + red[1] + red[2] + red[3];
}

__global__ void final_kernel(const float* __restrict__ partial, float* __restrict__ out)
{
    float v = partial[threadIdx.x];   // 64 threads
    #pragma unroll
    for (int d = 1; d < 64; d <<= 1) v += __shfl_xor(v, d);
    if (threadIdx.x == 0) out[0] = v * (LN2 / 16384.0f);
}

extern "C" void kernel_launch(void* const* d_in, const int* in_sizes, int n_in,
                              void* d_out, int out_size, void* d_ws, size_t ws_size,
                              hipStream_t stream)
{
    const float* z1 = (const float*)d_in[0];
    const float* z2 = (const float*)d_in[1];
    float* out = (float*)d_out;

    // ws: z1t bf16 [8][2048][256] (8MB) | z2t (8MB) | sum f32 [8][8][2048] | diag [8][2048] | partial[64]
    char* wsb = (char*)d_ws;
    unsigned short* z1t = (unsigned short*)wsb;
    unsigned short* z2t = (unsigned short*)(wsb + (8u << 20));
    float* ws_sum  = (float*)(wsb + (16u << 20));
    float* ws_diag = ws_sum + 8 * 8 * NN;
    float* ws_part = ws_diag + 8 * NN;

    transpose_kernel<<<dim3(2048), dim3(256), 0, stream>>>(z1, z2, z1t, z2t);
    gemm_lse_kernel<<<dim3(256), dim3(512), 0, stream>>>(z1t, z2t, ws_sum, ws_diag);
    merge_kernel<<<dim3(64), dim3(256), 0, stream>>>(ws_sum, ws_diag, ws_part);
    final_kernel<<<dim3(1), dim3(64), 0, stream>>>(ws_part, out);
}